// Round 1
// baseline (584.716 us; speedup 1.0000x reference)
//
#include <hip/hip_runtime.h>
#include <hip/hip_bf16.h>
#include <stdint.h>

#define DEV __device__ __forceinline__

typedef unsigned short u16;
typedef unsigned int u32;
typedef __bf16 bf16x8 __attribute__((ext_vector_type(8)));
typedef float f32x4 __attribute__((ext_vector_type(4)));
typedef float f32x4v __attribute__((ext_vector_type(4)));
typedef u16 u16x4 __attribute__((ext_vector_type(4)));

typedef __attribute__((address_space(1))) u32 u32_as1;
typedef __attribute__((address_space(3))) u32 u32_as3;

static constexpr int Bn = 4, Tn = 2048, Dm = 2048, Hn = 16, Dh = 128;
static constexpr int BT = Bn * Tn; // 8192

DEV u16 f2bf(float f) {
  u32 u = __builtin_bit_cast(u32, f);
  u += 0x7fffu + ((u >> 16) & 1u);   // RNE
  return (u16)(u >> 16);
}

// async 16B global->LDS. LDS dest is wave-linear (base + lane*16) — our layouts
// are linear in tid, swizzle is applied on the GLOBAL source side instead.
DEV void gl2lds16(const void* g, void* l) {
  __builtin_amdgcn_global_load_lds((u32_as1*)(uintptr_t)g,
                                   (u32_as3*)(u32)(uintptr_t)l, 16, 0, 0);
}

// ---------------- cast f32 -> bf16, vectorized x4 ----------------
__global__ __launch_bounds__(256) void k_cast_bf16(const float* __restrict__ in,
                                                   u16* __restrict__ out, int n4) {
  int i = blockIdx.x * 256 + threadIdx.x;
  int stride = gridDim.x * 256;
  for (; i < n4; i += stride) {
    f32x4v v = ((const f32x4v*)in)[i];
    u16x4 o;
    o.x = f2bf(v.x); o.y = f2bf(v.y); o.z = f2bf(v.z); o.w = f2bf(v.w);
    ((u16x4*)out)[i] = o;
  }
}

// ---------------- transpose-cast f32[R][C] -> bf16[C][R] ----------------
__global__ __launch_bounds__(256) void k_transpose_cast(const float* __restrict__ in,
                                                        u16* __restrict__ out,
                                                        int R, int C) {
  __shared__ float t[32][33];
  const int r0 = blockIdx.y * 32, c0 = blockIdx.x * 32;
  const int x = threadIdx.x, y = threadIdx.y; // (32,8)
#pragma unroll
  for (int i = 0; i < 4; ++i)
    t[y + i * 8][x] = in[(size_t)(r0 + y + i * 8) * C + c0 + x];
  __syncthreads();
#pragma unroll
  for (int i = 0; i < 4; ++i)
    out[(size_t)(c0 + y + i * 8) * R + r0 + x] = f2bf(t[x][y + i * 8]);
}

// ---------------- transpose bf16[R][C] -> bf16[C][R] ----------------
__global__ __launch_bounds__(256) void k_transpose_bf16(const u16* __restrict__ in,
                                                        u16* __restrict__ out,
                                                        int R, int C) {
  __shared__ u16 t[32][34];
  const int r0 = blockIdx.y * 32, c0 = blockIdx.x * 32;
  const int x = threadIdx.x, y = threadIdx.y;
#pragma unroll
  for (int i = 0; i < 4; ++i)
    t[y + i * 8][x] = in[(size_t)(r0 + y + i * 8) * C + c0 + x];
  __syncthreads();
#pragma unroll
  for (int i = 0; i < 4; ++i)
    out[(size_t)(c0 + y + i * 8) * R + r0 + x] = t[x][y + i * 8];
}

// ---------------- GEMM: C[M][N] = A[M][K] * Bt[N][K]^T + bias ----------------
// m97 structure: 128x128 tile, BK=64, 4 waves (2x2), global_load_lds w=16,
// XOR-swizzled LDS (byte ^= (row&7)<<4 within 128B row), ds_read_b128 frags.
template <typename OutT>
__global__ __launch_bounds__(256) void k_gemm_bt(const u16* __restrict__ A,
                                                 const u16* __restrict__ Bt,
                                                 const float* __restrict__ bias,
                                                 OutT* __restrict__ C,
                                                 int M, int N, int K) {
  __shared__ __align__(128) char smem[32768];
  char* As = smem;
  char* Bs = smem + 16384;
  const int tid = threadIdx.x;
  const int wid = tid >> 6, lane = tid & 63;
  const int g = lane >> 4, r = lane & 15;
  const int wr = wid >> 1, wc = wid & 1;
  const int m0 = blockIdx.x * 128, n0 = blockIdx.y * 128;

  f32x4 acc[4][4];
#pragma unroll
  for (int m = 0; m < 4; ++m)
#pragma unroll
    for (int n = 0; n < 4; ++n) acc[m][n] = (f32x4)(0.f);

  for (int k0 = 0; k0 < K; k0 += 64) {
#pragma unroll
    for (int n = 0; n < 4; ++n) {
      const int L = n * 4096 + tid * 16;
      const int row = L >> 7;               // 128B per LDS row (64 bf16)
      const int colb = (L & 127) ^ ((row & 7) << 4);  // pre-swizzled source
      gl2lds16((const char*)A + ((size_t)(m0 + row) * K + k0) * 2 + colb, As + L);
      gl2lds16((const char*)Bt + ((size_t)(n0 + row) * K + k0) * 2 + colb, Bs + L);
    }
    __syncthreads();
#pragma unroll
    for (int kk = 0; kk < 2; ++kk) {
      bf16x8 a[4], b[4];
#pragma unroll
      for (int m = 0; m < 4; ++m) {
        const int row = wr * 64 + m * 16 + r;
        a[m] = *(const bf16x8*)(As + row * 128 + ((kk * 64 + g * 16) ^ ((row & 7) << 4)));
      }
#pragma unroll
      for (int n = 0; n < 4; ++n) {
        const int row = wc * 64 + n * 16 + r;
        b[n] = *(const bf16x8*)(Bs + row * 128 + ((kk * 64 + g * 16) ^ ((row & 7) << 4)));
      }
#pragma unroll
      for (int m = 0; m < 4; ++m)
#pragma unroll
        for (int n = 0; n < 4; ++n)
          acc[m][n] = __builtin_amdgcn_mfma_f32_16x16x32_bf16(a[m], b[n], acc[m][n], 0, 0, 0);
    }
    __syncthreads();
  }

#pragma unroll
  for (int n = 0; n < 4; ++n) {
    const int col = n0 + wc * 64 + n * 16 + r;
    const float bv = bias[col];
#pragma unroll
    for (int m = 0; m < 4; ++m) {
#pragma unroll
      for (int j = 0; j < 4; ++j) {
        const int grow = m0 + wr * 64 + m * 16 + 4 * g + j;
        const float v = acc[m][n][j] + bv;
        if constexpr (sizeof(OutT) == 2)
          ((u16*)C)[(size_t)grow * N + col] = f2bf(v);
        else
          ((float*)C)[(size_t)grow * N + col] = v;
      }
    }
  }
}

// ---------------- flash attention (MQA), causal ----------------
// grid = B*H*(T/64); 4 waves x 16 q-rows. K staged [64][128] swz, VT staged
// [128][64] swz, P per-wave [16][64] swz LDS round-trip.
__global__ __launch_bounds__(256) void k_attn(const u16* __restrict__ Q,
                                              const u16* __restrict__ Kb,
                                              const u16* __restrict__ VT,
                                              u16* __restrict__ O) {
  __shared__ __align__(128) char smem[40960];
  char* Ks = smem;           // 16KB: [64 keys][256B]
  char* Vs = smem + 16384;   // 16KB: [128 d][128B]
  char* Ps = smem + 32768;   // 8KB:  4 waves x [16 q][128B]

  const int tid = threadIdx.x;
  const int wid = tid >> 6, lane = tid & 63;
  const int g = lane >> 4, r = lane & 15;

  const int bid = blockIdx.x;
  const int qb = bid & 31;
  const int h = (bid >> 5) & 15;
  const int b = bid >> 9;

  const int qrow0 = b * Tn + qb * 64 + wid * 16;

  bf16x8 qf[4];
#pragma unroll
  for (int c = 0; c < 4; ++c)
    qf[c] = *(const bf16x8*)(Q + (size_t)(qrow0 + r) * Dm + h * Dh + c * 32 + g * 8);

  f32x4 o[8];
#pragma unroll
  for (int c = 0; c < 8; ++c) o[c] = (f32x4)(0.f);
  float mrow[4] = {-1e30f, -1e30f, -1e30f, -1e30f};
  float lrow[4] = {0.f, 0.f, 0.f, 0.f};

  const float cl2 = 0.1275174147f; // log2(e)/sqrt(128)

  const int ntiles = qb + 1;
  for (int st = 0; st < ntiles; ++st) {
    const int s0 = b * Tn + st * 64;
#pragma unroll
    for (int n = 0; n < 4; ++n) {
      const int L = n * 4096 + tid * 16;
      { // K tile: LDS row = key (256B)
        const int row = L >> 8;
        const int colb = (L & 255) ^ ((row & 7) << 4);
        gl2lds16((const char*)Kb + ((size_t)(s0 + row) * Dh) * 2 + colb, Ks + L);
      }
      { // VT tile: LDS row = d (128B), global row stride BT
        const int row = L >> 7;
        const int colb = (L & 127) ^ ((row & 7) << 4);
        gl2lds16((const char*)VT + ((size_t)row * BT + s0) * 2 + colb, Vs + L);
      }
    }
    __syncthreads();

    const bool lastTile = (st == qb);
    f32x4 sf[4];
#pragma unroll
    for (int n = 0; n < 4; ++n) {
      f32x4 s = (f32x4)(0.f);
      if (!lastTile || n <= wid) {
#pragma unroll
        for (int c = 0; c < 4; ++c) {
          const int row = n * 16 + r;
          bf16x8 kf = *(const bf16x8*)(Ks + row * 256 + ((c * 64 + g * 16) ^ ((row & 7) << 4)));
          s = __builtin_amdgcn_mfma_f32_16x16x32_bf16(qf[c], kf, s, 0, 0, 0);
        }
      } else {
        s = (f32x4)(-1e30f);
      }
      sf[n] = s;
    }
    if (lastTile) {
#pragma unroll
      for (int n = 0; n < 4; ++n)
#pragma unroll
        for (int j = 0; j < 4; ++j) {
          const int key = n * 16 + r, qq = wid * 16 + 4 * g + j;
          if (key > qq) sf[n][j] = -1e30f;
        }
    }

    float fac[4];
#pragma unroll
    for (int j = 0; j < 4; ++j) {
      float v = fmaxf(fmaxf(sf[0][j], sf[1][j]), fmaxf(sf[2][j], sf[3][j]));
      v = fmaxf(v, __shfl_xor(v, 1));
      v = fmaxf(v, __shfl_xor(v, 2));
      v = fmaxf(v, __shfl_xor(v, 4));
      v = fmaxf(v, __shfl_xor(v, 8));
      const float mnew = fmaxf(mrow[j], v);
      fac[j] = __builtin_amdgcn_exp2f((mrow[j] - mnew) * cl2);
      mrow[j] = mnew;
    }

    u16 pb[4][4];
#pragma unroll
    for (int n = 0; n < 4; ++n)
#pragma unroll
      for (int j = 0; j < 4; ++j) {
        const float p = __builtin_amdgcn_exp2f((sf[n][j] - mrow[j]) * cl2);
        sf[n][j] = p;
        pb[n][j] = f2bf(p);
      }

#pragma unroll
    for (int j = 0; j < 4; ++j) {
      float v = sf[0][j] + sf[1][j] + sf[2][j] + sf[3][j];
      v += __shfl_xor(v, 1);
      v += __shfl_xor(v, 2);
      v += __shfl_xor(v, 4);
      v += __shfl_xor(v, 8);
      lrow[j] = lrow[j] * fac[j] + v;
    }
#pragma unroll
    for (int c = 0; c < 8; ++c)
#pragma unroll
      for (int j = 0; j < 4; ++j) o[c][j] *= fac[j];

    // P -> LDS (per-wave region, swizzled)
    char* Pw = Ps + wid * 2048;
#pragma unroll
    for (int n = 0; n < 4; ++n)
#pragma unroll
      for (int j = 0; j < 4; ++j) {
        const int row = 4 * g + j;
        *(u16*)(Pw + row * 128 + ((n * 32 + r * 2) ^ ((row & 7) << 4))) = pb[n][j];
      }

    // PV
#pragma unroll
    for (int kk = 0; kk < 2; ++kk) {
      if (lastTile && (kk * 32 > wid * 16 + 15)) continue; // fully-masked chunk
      bf16x8 pa = *(const bf16x8*)(Pw + r * 128 + ((kk * 64 + g * 16) ^ ((r & 7) << 4)));
#pragma unroll
      for (int c = 0; c < 8; ++c) {
        const int row = c * 16 + r;
        bf16x8 vb = *(const bf16x8*)(Vs + row * 128 + ((kk * 64 + g * 16) ^ ((row & 7) << 4)));
        o[c] = __builtin_amdgcn_mfma_f32_16x16x32_bf16(pa, vb, o[c], 0, 0, 0);
      }
    }
    __syncthreads();
  }

#pragma unroll
  for (int c = 0; c < 8; ++c)
#pragma unroll
    for (int j = 0; j < 4; ++j) {
      const float v = o[c][j] * __builtin_amdgcn_rcpf(lrow[j]);
      O[(size_t)(qrow0 + 4 * g + j) * Dm + h * Dh + c * 16 + r] = f2bf(v);
    }
}

// ---------------- host launch ----------------
extern "C" void kernel_launch(void* const* d_in, const int* in_sizes, int n_in,
                              void* d_out, int out_size, void* d_ws, size_t ws_size,
                              hipStream_t stream) {
  const float* x  = (const float*)d_in[0];
  // d_in[1] = mask: unused (exactly causal triu(-inf), applied analytically)
  const float* Wq = (const float*)d_in[2];
  const float* bq = (const float*)d_in[3];
  const float* Wk = (const float*)d_in[4];
  const float* bk = (const float*)d_in[5];
  const float* Wv = (const float*)d_in[6];
  const float* bv = (const float*)d_in[7];
  const float* Wo = (const float*)d_in[8];
  const float* bo = (const float*)d_in[9];
  float* out = (float*)d_out;

  char* ws = (char*)d_ws;
  size_t off = 0;
  auto alloc = [&](size_t bytes) {
    char* p = ws + off;
    off += (bytes + 255) & ~(size_t)255;
    return p;
  };
  // peak workspace ~91 MB (Ob aliases xb)
  u16* xb  = (u16*)alloc((size_t)BT * Dm * 2);
  u16* Qb  = (u16*)alloc((size_t)BT * Dm * 2);
  u16* Kb  = (u16*)alloc((size_t)BT * Dh * 2);
  u16* Vb  = (u16*)alloc((size_t)BT * Dh * 2);
  u16* VTb = (u16*)alloc((size_t)BT * Dh * 2);
  u16* Wqt = (u16*)alloc((size_t)Dm * Dm * 2);
  u16* Wkt = (u16*)alloc((size_t)Dm * Dh * 2);
  u16* Wvt = (u16*)alloc((size_t)Dm * Dh * 2);
  u16* Wot = (u16*)alloc((size_t)Dm * Dm * 2);
  u16* Ob  = xb; // x_bf16 is dead after the K/V/Q projections

  k_cast_bf16<<<2048, 256, 0, stream>>>(x, xb, BT * Dm / 4);
  dim3 tb(32, 8);
  k_transpose_cast<<<dim3(Dm / 32, Dm / 32), tb, 0, stream>>>(Wq, Wqt, Dm, Dm);
  k_transpose_cast<<<dim3(Dh / 32, Dm / 32), tb, 0, stream>>>(Wk, Wkt, Dm, Dh);
  k_transpose_cast<<<dim3(Dh / 32, Dm / 32), tb, 0, stream>>>(Wv, Wvt, Dm, Dh);
  k_transpose_cast<<<dim3(Dm / 32, Dm / 32), tb, 0, stream>>>(Wo, Wot, Dm, Dm);

  k_gemm_bt<u16><<<dim3(BT / 128, Dm / 128), 256, 0, stream>>>(xb, Wqt, bq, Qb, BT, Dm, Dm);
  k_gemm_bt<u16><<<dim3(BT / 128, Dh / 128), 256, 0, stream>>>(xb, Wkt, bk, Kb, BT, Dh, Dm);
  k_gemm_bt<u16><<<dim3(BT / 128, Dh / 128), 256, 0, stream>>>(xb, Wvt, bv, Vb, BT, Dh, Dm);
  k_transpose_bf16<<<dim3(Dh / 32, BT / 32), tb, 0, stream>>>(Vb, VTb, BT, Dh);

  k_attn<<<Bn * Hn * (Tn / 64), 256, 0, stream>>>(Qb, Kb, VTb, Ob);

  k_gemm_bt<float><<<dim3(BT / 128, Dm / 128), 256, 0, stream>>>(Ob, Wot, bo, out, BT, Dm, Dm);
}

// Round 3
// 375.458 us; speedup vs baseline: 1.5573x; 1.5573x over previous
//
#include <hip/hip_runtime.h>
#include <hip/hip_bf16.h>
#include <stdint.h>

#define DEV __device__ __forceinline__

typedef unsigned short u16;
typedef unsigned int u32;
typedef __bf16 bf16x8 __attribute__((ext_vector_type(8)));
typedef float f32x4 __attribute__((ext_vector_type(4)));
typedef u16 u16x4 __attribute__((ext_vector_type(4)));

typedef __attribute__((address_space(1))) u32 u32_as1;
typedef __attribute__((address_space(3))) u32 u32_as3;

static constexpr int Bn = 4, Tn = 2048, Dm = 2048, Hn = 16, Dh = 128;
static constexpr int BT = Bn * Tn; // 8192
static constexpr int KVSTR = 256;  // fused K|V row stride (elements)

#define VMCNT(n) asm volatile("s_waitcnt vmcnt(" #n ")" ::: "memory")
#define BARRIER() __builtin_amdgcn_s_barrier()

DEV u16 f2bf(float f) {
  u32 u = __builtin_bit_cast(u32, f);
  u += 0x7fffu + ((u >> 16) & 1u);   // RNE
  return (u16)(u >> 16);
}

// async 16B global->LDS; LDS dest is wave-linear (base + lane*16), so the
// XOR swizzle is applied on the GLOBAL source side (rule #21).
DEV void gl2lds16(const void* g, void* l) {
  __builtin_amdgcn_global_load_lds((u32_as1*)(uintptr_t)g,
                                   (u32_as3*)(u32)(uintptr_t)l, 16, 0, 0);
}

// ---------------- cast f32 -> bf16, vectorized x4 ----------------
__global__ __launch_bounds__(256) void k_cast_bf16(const float* __restrict__ in,
                                                   u16* __restrict__ out, int n4) {
  int i = blockIdx.x * 256 + threadIdx.x;
  int stride = gridDim.x * 256;
  for (; i < n4; i += stride) {
    f32x4 v = ((const f32x4*)in)[i];
    u16x4 o;
    o.x = f2bf(v.x); o.y = f2bf(v.y); o.z = f2bf(v.z); o.w = f2bf(v.w);
    ((u16x4*)out)[i] = o;
  }
}

// ---------------- transpose-cast f32[R][C] -> bf16[C][R] ----------------
__global__ __launch_bounds__(256) void k_transpose_cast(const float* __restrict__ in,
                                                        u16* __restrict__ out,
                                                        int R, int C) {
  __shared__ float t[32][33];
  const int r0 = blockIdx.y * 32, c0 = blockIdx.x * 32;
  const int x = threadIdx.x, y = threadIdx.y; // (32,8)
#pragma unroll
  for (int i = 0; i < 4; ++i)
    t[y + i * 8][x] = in[(size_t)(r0 + y + i * 8) * C + c0 + x];
  __syncthreads();
#pragma unroll
  for (int i = 0; i < 4; ++i)
    out[(size_t)(c0 + y + i * 8) * R + r0 + x] = f2bf(t[x][y + i * 8]);
}

// ---------------- transpose bf16 in[R][inStride] (window C) -> out[C][R] ----
__global__ __launch_bounds__(256) void k_transpose_bf16(const u16* __restrict__ in,
                                                        int inStride,
                                                        u16* __restrict__ out,
                                                        int R, int C) {
  __shared__ u16 t[32][34];
  const int r0 = blockIdx.y * 32, c0 = blockIdx.x * 32;
  const int x = threadIdx.x, y = threadIdx.y;
#pragma unroll
  for (int i = 0; i < 4; ++i)
    t[y + i * 8][x] = in[(size_t)(r0 + y + i * 8) * inStride + c0 + x];
  __syncthreads();
#pragma unroll
  for (int i = 0; i < 4; ++i)
    out[(size_t)(c0 + y + i * 8) * R + r0 + x] = t[x][y + i * 8];
}

__global__ void k_concat_bias(const float* __restrict__ a, const float* __restrict__ b,
                              float* __restrict__ dst) {
  int i = threadIdx.x; // 256
  dst[i] = (i < 128) ? a[i] : b[i - 128];
}

// ---------------- GEMM: C[M][N] = A[M][K] * Bt[N][K]^T + bias ----------------
// m97 structure: 128x128 tile, BK=64, 4 waves (2x2), global_load_lds w=16,
// XOR-swizzled LDS, ds_read_b128 fragments.
template <typename OutT>
__global__ __launch_bounds__(256) void k_gemm_bt(const u16* __restrict__ A,
                                                 const u16* __restrict__ Bt,
                                                 const float* __restrict__ bias,
                                                 OutT* __restrict__ C,
                                                 int M, int N, int K) {
  __shared__ __align__(128) char smem[32768];
  char* As = smem;
  char* Bs = smem + 16384;
  const int tid = threadIdx.x;
  const int wid = tid >> 6, lane = tid & 63;
  const int g = lane >> 4, r = lane & 15;
  const int wr = wid >> 1, wc = wid & 1;
  const int m0 = blockIdx.x * 128, n0 = blockIdx.y * 128;

  f32x4 acc[4][4];
#pragma unroll
  for (int m = 0; m < 4; ++m)
#pragma unroll
    for (int n = 0; n < 4; ++n) acc[m][n] = (f32x4)(0.f);

  for (int k0 = 0; k0 < K; k0 += 64) {
#pragma unroll
    for (int n = 0; n < 4; ++n) {
      const int L = n * 4096 + tid * 16;
      const int row = L >> 7;               // 128B per LDS row (64 bf16)
      const int colb = (L & 127) ^ ((row & 7) << 4);  // pre-swizzled source
      gl2lds16((const char*)A + ((size_t)(m0 + row) * K + k0) * 2 + colb, As + L);
      gl2lds16((const char*)Bt + ((size_t)(n0 + row) * K + k0) * 2 + colb, Bs + L);
    }
    __syncthreads();
#pragma unroll
    for (int kk = 0; kk < 2; ++kk) {
      bf16x8 a[4], b[4];
#pragma unroll
      for (int m = 0; m < 4; ++m) {
        const int row = wr * 64 + m * 16 + r;
        a[m] = *(const bf16x8*)(As + row * 128 + ((kk * 64 + g * 16) ^ ((row & 7) << 4)));
      }
#pragma unroll
      for (int n = 0; n < 4; ++n) {
        const int row = wc * 64 + n * 16 + r;
        b[n] = *(const bf16x8*)(Bs + row * 128 + ((kk * 64 + g * 16) ^ ((row & 7) << 4)));
      }
#pragma unroll
      for (int m = 0; m < 4; ++m)
#pragma unroll
        for (int n = 0; n < 4; ++n)
          acc[m][n] = __builtin_amdgcn_mfma_f32_16x16x32_bf16(a[m], b[n], acc[m][n], 0, 0, 0);
    }
    __syncthreads();
  }

#pragma unroll
  for (int n = 0; n < 4; ++n) {
    const int col = n0 + wc * 64 + n * 16 + r;
    const float bv = bias[col];
#pragma unroll
    for (int m = 0; m < 4; ++m) {
#pragma unroll
      for (int j = 0; j < 4; ++j) {
        const int grow = m0 + wr * 64 + m * 16 + 4 * g + j;
        const float v = acc[m][n][j] + bv;
        if constexpr (sizeof(OutT) == 2)
          ((u16*)C)[(size_t)grow * N + col] = f2bf(v);
        else
          ((float*)C)[(size_t)grow * N + col] = v;
      }
    }
  }
}

// ---------------- flash attention (MQA), causal ----------------
// 512 uniform blocks (causal pairing: q-tiles p and 15-p, 34 kv-tiles each).
// 4 waves x 32 q-rows. Double-buffered K (prefetch K_{t+1}), single V,
// counted vmcnt + raw barriers so prefetch stays in flight across barriers.
__global__ __launch_bounds__(256, 2) void k_attn(const u16* __restrict__ Q,
                                                 const u16* __restrict__ Kb,
                                                 const u16* __restrict__ VT,
                                                 u16* __restrict__ O) {
  __shared__ __align__(1024) char smem[65536];
  // layout: K dbuf at smem + (cur<<14)  (2 x 16KB, [64 keys][256B] swizzled)
  char* Vs = smem + 32768;                   // V^T: [128 d][128B], swizzled
  char* Ps = smem + 49152;                   // per-wave [32 q][128B]

  const int tid = threadIdx.x;
  const int wq = tid >> 6, lane = tid & 63;
  const int g = lane >> 4, r = lane & 15;

  // XCD-aware decode: hw xcd = blockIdx % 8; give each batch 2 XCDs.
  const int bid = blockIdx.x;
  const int xcd = bid & 7, ii = bid >> 3;
  const int b = xcd >> 1;
  const int h = ((xcd & 1) << 3) | (ii >> 3);
  const int p = ii & 7;
  const int qtA = p, qtB = 15 - p;
  const int nstA = 2 * qtA + 2;
  const int ntot = nstA + 2 * qtB + 2;       // = 34

  const float cl2 = 0.1275174147f; // log2(e)/sqrt(128)

  bf16x8 qf[2][4];
  f32x4 o[2][8];
  float mrow[2][4], lrow[2][4];

  auto loadQ = [&](int qrow0) {
#pragma unroll
    for (int m2 = 0; m2 < 2; ++m2)
#pragma unroll
      for (int c = 0; c < 4; ++c)
        qf[m2][c] = *(const bf16x8*)(Q + (size_t)(qrow0 + m2 * 16 + r) * Dm + h * Dh + c * 32 + g * 8);
  };
  auto resetAcc = [&]() {
#pragma unroll
    for (int m2 = 0; m2 < 2; ++m2) {
#pragma unroll
      for (int c = 0; c < 8; ++c) o[m2][c] = (f32x4)(0.f);
#pragma unroll
      for (int j = 0; j < 4; ++j) { mrow[m2][j] = -1e30f; lrow[m2][j] = 0.f; }
    }
  };
  auto storeO = [&](int qrow0) {
#pragma unroll
    for (int m2 = 0; m2 < 2; ++m2)
#pragma unroll
      for (int c = 0; c < 8; ++c)
#pragma unroll
        for (int j = 0; j < 4; ++j) {
          const float v = o[m2][c][j] * __builtin_amdgcn_rcpf(lrow[m2][j]);
          O[(size_t)(qrow0 + m2 * 16 + 4 * g + j) * Dm + h * Dh + c * 16 + r] = f2bf(v);
        }
  };
  auto stageK = [&](int s0, char* dst) {
#pragma unroll
    for (int n = 0; n < 4; ++n) {
      const int L = n * 4096 + tid * 16;
      const int row = L >> 8;                          // key within tile
      const int colb = (L & 255) ^ ((row & 7) << 4);
      gl2lds16((const char*)Kb + (size_t)(s0 + row) * (KVSTR * 2) + colb, dst + L);
    }
  };
  auto stageV = [&](int s0) {
#pragma unroll
    for (int n = 0; n < 4; ++n) {
      const int L = n * 4096 + tid * 16;
      const int row = L >> 7;                          // d
      const int colb = (L & 127) ^ ((row & 7) << 4);
      gl2lds16((const char*)VT + ((size_t)row * BT + s0) * 2 + colb, Vs + L);
    }
  };

  int qt = qtA;
  int qrow0 = b * Tn + qt * 128 + wq * 32;
  int qmin = qt * 128 + wq * 32;
  loadQ(qrow0);
  resetAcc();
  stageK(b * Tn, smem);
  VMCNT(0);
  BARRIER();

  int cur = 0;
  for (int t = 0; t < ntot; ++t) {
    if (t == nstA) { // switch to second q-tile
      storeO(qrow0);
      qt = qtB;
      qrow0 = b * Tn + qt * 128 + wq * 32;
      qmin = qt * 128 + wq * 32;
      loadQ(qrow0);
      resetAcc();
    }
    const int st = (t < nstA) ? t : t - nstA;
    const int s0 = b * Tn + st * 64;

    // issue V_t, then prefetch K_{t+1} into the other buffer
    stageV(s0);
    {
      const int t1 = t + 1;
      const int st1 = (t1 >= ntot) ? 0 : ((t1 < nstA) ? t1 : t1 - nstA);
      stageK(b * Tn + st1 * 64, smem + ((cur ^ 1) << 14));
    }

    const bool fullmask = (st * 64 >= qmin + 32); // wave-uniform
    char* Pw = Ps + wq * 4096;
    if (!fullmask) {
      const char* Kc = smem + (cur << 14);
      f32x4 sf[2][4];
#pragma unroll
      for (int n = 0; n < 4; ++n) {
        f32x4 sa = (f32x4)(0.f), sb = (f32x4)(0.f);
#pragma unroll
        for (int c = 0; c < 4; ++c) {
          const int row = n * 16 + r;
          bf16x8 kf = *(const bf16x8*)(Kc + row * 256 + ((c * 64 + g * 16) ^ ((row & 7) << 4)));
          sa = __builtin_amdgcn_mfma_f32_16x16x32_bf16(qf[0][c], kf, sa, 0, 0, 0);
          sb = __builtin_amdgcn_mfma_f32_16x16x32_bf16(qf[1][c], kf, sb, 0, 0, 0);
        }
        sf[0][n] = sa; sf[1][n] = sb;
      }
      if (st * 64 + 63 > qmin) { // partial tile: element mask key > q
#pragma unroll
        for (int m2 = 0; m2 < 2; ++m2)
#pragma unroll
          for (int n = 0; n < 4; ++n)
#pragma unroll
            for (int j = 0; j < 4; ++j) {
              const int key = st * 64 + n * 16 + r;
              const int q = qmin + m2 * 16 + 4 * g + j;
              if (key > q) sf[m2][n][j] = -1e30f;
            }
      }
      float fac[2][4];
#pragma unroll
      for (int m2 = 0; m2 < 2; ++m2)
#pragma unroll
        for (int j = 0; j < 4; ++j) {
          float v = fmaxf(fmaxf(sf[m2][0][j], sf[m2][1][j]), fmaxf(sf[m2][2][j], sf[m2][3][j]));
          v = fmaxf(v, __shfl_xor(v, 1));
          v = fmaxf(v, __shfl_xor(v, 2));
          v = fmaxf(v, __shfl_xor(v, 4));
          v = fmaxf(v, __shfl_xor(v, 8));
          const float mnew = fmaxf(mrow[m2][j], v);
          fac[m2][j] = __builtin_amdgcn_exp2f((mrow[m2][j] - mnew) * cl2);
          mrow[m2][j] = mnew;
        }
#pragma unroll
      for (int m2 = 0; m2 < 2; ++m2)
#pragma unroll
        for (int n = 0; n < 4; ++n)
#pragma unroll
          for (int j = 0; j < 4; ++j) {
            const float pv = __builtin_amdgcn_exp2f((sf[m2][n][j] - mrow[m2][j]) * cl2);
            sf[m2][n][j] = pv;
            const int row = m2 * 16 + 4 * g + j;
            *(u16*)(Pw + row * 128 + ((n * 32 + r * 2) ^ ((row & 7) << 4))) = f2bf(pv);
          }
#pragma unroll
      for (int m2 = 0; m2 < 2; ++m2)
#pragma unroll
        for (int j = 0; j < 4; ++j) {
          float v = sf[m2][0][j] + sf[m2][1][j] + sf[m2][2][j] + sf[m2][3][j];
          v += __shfl_xor(v, 1);
          v += __shfl_xor(v, 2);
          v += __shfl_xor(v, 4);
          v += __shfl_xor(v, 8);
          lrow[m2][j] = lrow[m2][j] * fac[m2][j] + v;
        }
#pragma unroll
      for (int m2 = 0; m2 < 2; ++m2)
#pragma unroll
        for (int c = 0; c < 8; ++c)
#pragma unroll
          for (int j = 0; j < 4; ++j) o[m2][c][j] *= fac[m2][j];
    }

    VMCNT(4);   // own V loads done (K prefetch, 4 newest, may stay in flight)
    BARRIER();  // all waves' V parts landed in LDS

    if (!fullmask) {
#pragma unroll
      for (int kk = 0; kk < 2; ++kk) {
        if (st * 64 + kk * 32 >= qmin + 32) continue; // fully-masked half
        bf16x8 pa0 = *(const bf16x8*)(Pw + r * 128 + ((kk * 64 + g * 16) ^ ((r & 7) << 4)));
        bf16x8 pa1 = *(const bf16x8*)(Pw + (16 + r) * 128 + ((kk * 64 + g * 16) ^ ((r & 7) << 4)));
#pragma unroll
        for (int c = 0; c < 8; ++c) {
          const int row = c * 16 + r;
          bf16x8 vb = *(const bf16x8*)(Vs + row * 128 + ((kk * 64 + g * 16) ^ ((row & 7) << 4)));
          o[0][c] = __builtin_amdgcn_mfma_f32_16x16x32_bf16(pa0, vb, o[0][c], 0, 0, 0);
          o[1][c] = __builtin_amdgcn_mfma_f32_16x16x32_bf16(pa1, vb, o[1][c], 0, 0, 0);
        }
      }
    }

    VMCNT(0);   // K_{t+1} landed (issued a full tile ago)
    BARRIER();  // safe to overwrite Vs / read Ks[cur^1] next iteration
    cur ^= 1;
  }
  storeO(qrow0);
}

// ---------------- host launch ----------------
extern "C" void kernel_launch(void* const* d_in, const int* in_sizes, int n_in,
                              void* d_out, int out_size, void* d_ws, size_t ws_size,
                              hipStream_t stream) {
  const float* x  = (const float*)d_in[0];
  // d_in[1] = mask: unused (exactly causal triu(-inf), applied analytically)
  const float* Wq = (const float*)d_in[2];
  const float* bq = (const float*)d_in[3];
  const float* Wk = (const float*)d_in[4];
  const float* bk = (const float*)d_in[5];
  const float* Wv = (const float*)d_in[6];
  const float* bv = (const float*)d_in[7];
  const float* Wo = (const float*)d_in[8];
  const float* bo = (const float*)d_in[9];
  float* out = (float*)d_out;

  char* ws = (char*)d_ws;
  size_t off = 0;
  auto alloc = [&](size_t bytes) {
    char* p = ws + off;
    off += (bytes + 255) & ~(size_t)255;
    return p;
  };
  u16* xb   = (u16*)alloc((size_t)BT * Dm * 2);
  u16* Qb   = (u16*)alloc((size_t)BT * Dm * 2);
  u16* KVb  = (u16*)alloc((size_t)BT * KVSTR * 2);   // [token][K(128)|V(128)]
  u16* VTb  = (u16*)alloc((size_t)BT * Dh * 2);
  u16* Wqt  = (u16*)alloc((size_t)Dm * Dm * 2);
  u16* Wkvt = (u16*)alloc((size_t)Dm * KVSTR * 2);   // [K^T rows | V^T rows]
  u16* Wot  = (u16*)alloc((size_t)Dm * Dm * 2);
  float* bkv = (float*)alloc(KVSTR * sizeof(float));
  u16* Ob   = xb; // x_bf16 dead after projections

  k_cast_bf16<<<2048, 256, 0, stream>>>(x, xb, BT * Dm / 4);
  dim3 tb(32, 8);
  k_transpose_cast<<<dim3(Dm / 32, Dm / 32), tb, 0, stream>>>(Wq, Wqt, Dm, Dm);
  k_transpose_cast<<<dim3(Dh / 32, Dm / 32), tb, 0, stream>>>(Wk, Wkvt, Dm, Dh);
  k_transpose_cast<<<dim3(Dh / 32, Dm / 32), tb, 0, stream>>>(Wv, Wkvt + (size_t)Dh * Dm, Dm, Dh);
  k_transpose_cast<<<dim3(Dm / 32, Dm / 32), tb, 0, stream>>>(Wo, Wot, Dm, Dm);
  k_concat_bias<<<1, 256, 0, stream>>>(bk, bv, bkv);

  k_gemm_bt<u16><<<dim3(BT / 128, Dm / 128), 256, 0, stream>>>(xb, Wqt, bq, Qb, BT, Dm, Dm);
  k_gemm_bt<u16><<<dim3(BT / 128, KVSTR / 128), 256, 0, stream>>>(xb, Wkvt, bkv, KVb, BT, KVSTR, Dm);
  k_transpose_bf16<<<dim3(Dh / 32, BT / 32), tb, 0, stream>>>(KVb + Dh, KVSTR, VTb, BT, Dh);

  k_attn<<<512, 256, 0, stream>>>(Qb, KVb, VTb, Ob);

  k_gemm_bt<float><<<dim3(BT / 128, Dm / 128), 256, 0, stream>>>(Ob, Wot, bo, out, BT, Dm, Dm);
}

// Round 4
// 352.222 us; speedup vs baseline: 1.6601x; 1.0660x over previous
//
#include <hip/hip_runtime.h>
#include <hip/hip_bf16.h>
#include <stdint.h>

#define DEV __device__ __forceinline__

typedef unsigned short u16;
typedef unsigned int u32;
typedef __bf16 bf16x8 __attribute__((ext_vector_type(8)));
typedef float f32x4 __attribute__((ext_vector_type(4)));
typedef u16 u16x4 __attribute__((ext_vector_type(4)));

typedef __attribute__((address_space(1))) u32 u32_as1;
typedef __attribute__((address_space(3))) u32 u32_as3;

static constexpr int Bn = 4, Tn = 2048, Dm = 2048, Hn = 16, Dh = 128;
static constexpr int BT = Bn * Tn; // 8192
static constexpr int KVSTR = 256;  // fused K|V row stride (elements)

#define VMCNT(n) asm volatile("s_waitcnt vmcnt(" #n ")" ::: "memory")
#define BARRIER() __builtin_amdgcn_s_barrier()

DEV u16 f2bf(float f) {
  u32 u = __builtin_bit_cast(u32, f);
  u += 0x7fffu + ((u >> 16) & 1u);   // RNE
  return (u16)(u >> 16);
}
DEV u16 cvt_bf(float f) { return __builtin_bit_cast(u16, (__bf16)f); }

// async 16B global->LDS; LDS dest is wave-linear (base + lane*16), so the
// XOR swizzle is applied on the GLOBAL source side (rule #21).
DEV void gl2lds16(const void* g, void* l) {
  __builtin_amdgcn_global_load_lds((u32_as1*)(uintptr_t)g,
                                   (u32_as3*)(u32)(uintptr_t)l, 16, 0, 0);
}

// ---------------- cast f32 -> bf16, vectorized x4 ----------------
__global__ __launch_bounds__(256) void k_cast_bf16(const float* __restrict__ in,
                                                   u16* __restrict__ out, int n4) {
  int i = blockIdx.x * 256 + threadIdx.x;
  int stride = gridDim.x * 256;
  for (; i < n4; i += stride) {
    f32x4 v = ((const f32x4*)in)[i];
    u16x4 o;
    o.x = f2bf(v.x); o.y = f2bf(v.y); o.z = f2bf(v.z); o.w = f2bf(v.w);
    ((u16x4*)out)[i] = o;
  }
}

// ---------------- transpose-cast f32[R][C] -> bf16[C][R] ----------------
__global__ __launch_bounds__(256) void k_transpose_cast(const float* __restrict__ in,
                                                        u16* __restrict__ out,
                                                        int R, int C) {
  __shared__ float t[32][33];
  const int r0 = blockIdx.y * 32, c0 = blockIdx.x * 32;
  const int x = threadIdx.x, y = threadIdx.y; // (32,8)
#pragma unroll
  for (int i = 0; i < 4; ++i)
    t[y + i * 8][x] = in[(size_t)(r0 + y + i * 8) * C + c0 + x];
  __syncthreads();
#pragma unroll
  for (int i = 0; i < 4; ++i)
    out[(size_t)(c0 + y + i * 8) * R + r0 + x] = f2bf(t[x][y + i * 8]);
}

// ---------------- transpose bf16 in[R][inStride] (window C) -> out[C][R] ----
__global__ __launch_bounds__(256) void k_transpose_bf16(const u16* __restrict__ in,
                                                        int inStride,
                                                        u16* __restrict__ out,
                                                        int R, int C) {
  __shared__ u16 t[32][34];
  const int r0 = blockIdx.y * 32, c0 = blockIdx.x * 32;
  const int x = threadIdx.x, y = threadIdx.y;
#pragma unroll
  for (int i = 0; i < 4; ++i)
    t[y + i * 8][x] = in[(size_t)(r0 + y + i * 8) * inStride + c0 + x];
  __syncthreads();
#pragma unroll
  for (int i = 0; i < 4; ++i)
    out[(size_t)(c0 + y + i * 8) * R + r0 + x] = t[x][y + i * 8];
}

__global__ void k_concat_bias(const float* __restrict__ a, const float* __restrict__ b,
                              float* __restrict__ dst) {
  int i = threadIdx.x; // 256
  dst[i] = (i < 128) ? a[i] : b[i - 128];
}

// ---------------- GEMM 128x128 (m97 structure) — used for the small KV proj ----
template <typename OutT>
__global__ __launch_bounds__(256) void k_gemm_bt(const u16* __restrict__ A,
                                                 const u16* __restrict__ Bt,
                                                 const float* __restrict__ bias,
                                                 OutT* __restrict__ C,
                                                 int M, int N, int K) {
  __shared__ __align__(128) char smem[32768];
  char* As = smem;
  char* Bs = smem + 16384;
  const int tid = threadIdx.x;
  const int wid = tid >> 6, lane = tid & 63;
  const int g = lane >> 4, r = lane & 15;
  const int wr = wid >> 1, wc = wid & 1;
  const int m0 = blockIdx.x * 128, n0 = blockIdx.y * 128;

  f32x4 acc[4][4];
#pragma unroll
  for (int m = 0; m < 4; ++m)
#pragma unroll
    for (int n = 0; n < 4; ++n) acc[m][n] = (f32x4)(0.f);

  for (int k0 = 0; k0 < K; k0 += 64) {
#pragma unroll
    for (int n = 0; n < 4; ++n) {
      const int L = n * 4096 + tid * 16;
      const int row = L >> 7;
      const int colb = (L & 127) ^ ((row & 7) << 4);
      gl2lds16((const char*)A + ((size_t)(m0 + row) * K + k0) * 2 + colb, As + L);
      gl2lds16((const char*)Bt + ((size_t)(n0 + row) * K + k0) * 2 + colb, Bs + L);
    }
    __syncthreads();
#pragma unroll
    for (int kk = 0; kk < 2; ++kk) {
      bf16x8 a[4], b[4];
#pragma unroll
      for (int m = 0; m < 4; ++m) {
        const int row = wr * 64 + m * 16 + r;
        a[m] = *(const bf16x8*)(As + row * 128 + ((kk * 64 + g * 16) ^ ((row & 7) << 4)));
      }
#pragma unroll
      for (int n = 0; n < 4; ++n) {
        const int row = wc * 64 + n * 16 + r;
        b[n] = *(const bf16x8*)(Bs + row * 128 + ((kk * 64 + g * 16) ^ ((row & 7) << 4)));
      }
#pragma unroll
      for (int m = 0; m < 4; ++m)
#pragma unroll
        for (int n = 0; n < 4; ++n)
          acc[m][n] = __builtin_amdgcn_mfma_f32_16x16x32_bf16(a[m], b[n], acc[m][n], 0, 0, 0);
    }
    __syncthreads();
  }

#pragma unroll
  for (int n = 0; n < 4; ++n) {
    const int col = n0 + wc * 64 + n * 16 + r;
    const float bv = bias[col];
#pragma unroll
    for (int m = 0; m < 4; ++m) {
#pragma unroll
      for (int j = 0; j < 4; ++j) {
        const int grow = m0 + wr * 64 + m * 16 + 4 * g + j;
        const float v = acc[m][n][j] + bv;
        if constexpr (sizeof(OutT) == 2)
          ((u16*)C)[(size_t)grow * N + col] = f2bf(v);
        else
          ((float*)C)[(size_t)grow * N + col] = v;
      }
    }
  }
}

// ---------------- GEMM 256x256, 8-wave, 4-phase/K-tile, counted vmcnt ----------
// BM=BN=256, BK=64, 8 waves (2m x 4n), per-wave out 128x64. LDS 128KB (dynamic):
// dbuf x (A 32KB + B 32KB). Staging partitioned per wave class so each wave's
// own 8 loads/K-tile are exactly its consumed halves -> vmcnt(8) at phase 4
// waits tile t+1 complete while tile t+2's 8 loads stay in flight (T3+T4).
template <typename OutT>
__global__ __launch_bounds__(512, 2) void k_gemm256(const u16* __restrict__ A,
                                                    const u16* __restrict__ Bt,
                                                    const float* __restrict__ bias,
                                                    OutT* __restrict__ C,
                                                    int M, int N, int K) {
  extern __shared__ char smem[];
  const int tid = threadIdx.x;
  const int wid = tid >> 6, lane = tid & 63;
  const int g = lane >> 4, r = lane & 15;
  const int wm = wid >> 2, wn = wid & 3;

  // XCD swizzle (grid % 8 == 0 for our shapes)
  const int nbn = N >> 8;
  const int cpx = gridDim.x >> 3;
  const int linear = (blockIdx.x & 7) * cpx + (blockIdx.x >> 3);
  const int m0 = (linear / nbn) << 8;
  const int n0 = (linear % nbn) << 8;

  // per-thread staging sources: 4 A-chunks (wave class wm) + 4 B-chunks (class wnh)
  const int rowInCh = lane >> 3;                       // 0..7
  const int colb = ((lane & 7) << 4) ^ (rowInCh << 4); // pre-swizzled source col
  const char* srcA0; const char* srcA1; const char* srcA2; const char* srcA3;
  const char* srcB0; const char* srcB1; const char* srcB2; const char* srcB3;
  int ldsA[4], ldsB[4];
  {
    const int wnh = (wid >> 1) & 1;
    const int cbb = ((wid >> 2) << 1) | (wid & 1);
    const char* sa[4]; const char* sb[4];
#pragma unroll
    for (int i = 0; i < 4; ++i) {
      const int chA = ((wid & 3) << 2) + i;            // 0..15
      const int lrA = (wm << 7) + (chA << 3) + rowInCh;
      sa[i] = (const char*)A + ((size_t)(m0 + lrA) * K) * 2 + colb;
      ldsA[i] = ((wm << 7) + (chA << 3)) * 128 + lane * 16;
      const int chB = (cbb << 2) + i;
      const int lrB = (wnh << 7) + (chB << 3) + rowInCh;
      sb[i] = (const char*)Bt + ((size_t)(n0 + lrB) * K) * 2 + colb;
      ldsB[i] = 32768 + ((wnh << 7) + (chB << 3)) * 128 + lane * 16;
    }
    srcA0 = sa[0]; srcA1 = sa[1]; srcA2 = sa[2]; srcA3 = sa[3];
    srcB0 = sb[0]; srcB1 = sb[1]; srcB2 = sb[2]; srcB3 = sb[3];
  }

  auto stage = [&](int t, int b) {
    const size_t ko = (size_t)t * 128;   // 64 bf16 per K-tile = 128 bytes
    char* base = smem + (b << 16);
    gl2lds16(srcA0 + ko, base + ldsA[0]);
    gl2lds16(srcA1 + ko, base + ldsA[1]);
    gl2lds16(srcA2 + ko, base + ldsA[2]);
    gl2lds16(srcA3 + ko, base + ldsA[3]);
    gl2lds16(srcB0 + ko, base + ldsB[0]);
    gl2lds16(srcB1 + ko, base + ldsB[1]);
    gl2lds16(srcB2 + ko, base + ldsB[2]);
    gl2lds16(srcB3 + ko, base + ldsB[3]);
  };

  f32x4 acc[8][4];
#pragma unroll
  for (int m = 0; m < 8; ++m)
#pragma unroll
    for (int n = 0; n < 4; ++n) acc[m][n] = (f32x4)(0.f);

  auto readA = [&](const char* Ab, int qm, bf16x8 (&a)[8]) {
#pragma unroll
    for (int m = 0; m < 4; ++m) {
      const int row = (wm << 7) + ((qm * 4 + m) << 4) + r;
#pragma unroll
      for (int kk = 0; kk < 2; ++kk)
        a[m * 2 + kk] = *(const bf16x8*)(Ab + row * 128 + ((kk * 64 + g * 16) ^ ((row & 7) << 4)));
    }
  };
  auto readB = [&](const char* Bb, int qn, bf16x8 (&b)[4]) {
#pragma unroll
    for (int n = 0; n < 2; ++n) {
      const int row = (wn << 6) + ((qn * 2 + n) << 4) + r;
#pragma unroll
      for (int kk = 0; kk < 2; ++kk)
        b[n * 2 + kk] = *(const bf16x8*)(Bb + row * 128 + ((kk * 64 + g * 16) ^ ((row & 7) << 4)));
    }
  };
  auto mfmaQ = [&](const bf16x8 (&a)[8], const bf16x8 (&b)[4], int qm, int qn) {
    __builtin_amdgcn_s_setprio(1);
#pragma unroll
    for (int m = 0; m < 4; ++m)
#pragma unroll
      for (int n = 0; n < 2; ++n)
#pragma unroll
        for (int kk = 0; kk < 2; ++kk)
          acc[qm * 4 + m][qn * 2 + n] = __builtin_amdgcn_mfma_f32_16x16x32_bf16(
              a[m * 2 + kk], b[n * 2 + kk], acc[qm * 4 + m][qn * 2 + n], 0, 0, 0);
    __builtin_amdgcn_s_setprio(0);
  };

  const int NT = K >> 6;
  stage(0, 0);
  stage(1, 1);
  VMCNT(8);
  BARRIER();

  bf16x8 a0[8], a1[8], b0[4], b1[4];
  for (int t = 0; t < NT; ++t) {
    const char* Ab = smem + ((t & 1) << 16);
    const char* Bb = Ab + 32768;
    // phase 1
    readA(Ab, 0, a0);
    readB(Bb, 0, b0);
    BARRIER();
    mfmaQ(a0, b0, 0, 0);
    BARRIER();
    // phase 2
    readB(Bb, 1, b1);
    BARRIER();
    mfmaQ(a0, b1, 0, 1);
    BARRIER();
    // phase 3
    readA(Ab, 1, a1);
    BARRIER();
    mfmaQ(a1, b1, 1, 1);
    BARRIER();
    // phase 4 (no ds_read; tile t buffer dead after p3's barrier)
    if (t + 2 < NT) {
      stage(t + 2, t & 1);
      mfmaQ(a1, b0, 1, 0);
      VMCNT(8);           // tile t+1 landed; t+2's 8 loads stay in flight
    } else {
      mfmaQ(a1, b0, 1, 0);
      VMCNT(0);           // epilogue drain
    }
    BARRIER();
  }

#pragma unroll
  for (int n = 0; n < 4; ++n) {
    const int col = n0 + wn * 64 + n * 16 + r;
    const float bv = bias[col];
#pragma unroll
    for (int m = 0; m < 8; ++m) {
#pragma unroll
      for (int j = 0; j < 4; ++j) {
        const int grow = m0 + wm * 128 + m * 16 + 4 * g + j;
        const float v = acc[m][n][j] + bv;
        if constexpr (sizeof(OutT) == 2)
          ((u16*)C)[(size_t)grow * N + col] = cvt_bf(v);
        else
          ((float*)C)[(size_t)grow * N + col] = v;
      }
    }
  }
}

// ---------------- flash attention (MQA), causal ----------------
// 512 uniform blocks (causal pairing). 4 waves x 32 q-rows. Dbuf K prefetch,
// counted vmcnt; T13 defer-rescale; T5 setprio; native bf16 cvt.
__global__ __launch_bounds__(256, 2) void k_attn(const u16* __restrict__ Q,
                                                 const u16* __restrict__ Kb,
                                                 const u16* __restrict__ VT,
                                                 u16* __restrict__ O) {
  __shared__ __align__(1024) char smem[65536];
  char* Vs = smem + 32768;                   // V^T: [128 d][128B], swizzled
  char* Ps = smem + 49152;                   // per-wave [32 q][128B]

  const int tid = threadIdx.x;
  const int wq = tid >> 6, lane = tid & 63;
  const int g = lane >> 4, r = lane & 15;

  const int bid = blockIdx.x;
  const int xcd = bid & 7, ii = bid >> 3;
  const int b = xcd >> 1;
  const int h = ((xcd & 1) << 3) | (ii >> 3);
  const int p = ii & 7;
  const int qtA = p, qtB = 15 - p;
  const int nstA = 2 * qtA + 2;
  const int ntot = nstA + 2 * qtB + 2;       // = 34

  const float cl2 = 0.1275174147f;           // log2(e)/sqrt(128)
  const float DEFER = 62.736f;               // 8 / cl2

  bf16x8 qf[2][4];
  f32x4 o[2][8];
  float mrow[2][4], lrow[2][4];

  auto loadQ = [&](int qrow0) {
#pragma unroll
    for (int m2 = 0; m2 < 2; ++m2)
#pragma unroll
      for (int c = 0; c < 4; ++c)
        qf[m2][c] = *(const bf16x8*)(Q + (size_t)(qrow0 + m2 * 16 + r) * Dm + h * Dh + c * 32 + g * 8);
  };
  auto resetAcc = [&]() {
#pragma unroll
    for (int m2 = 0; m2 < 2; ++m2) {
#pragma unroll
      for (int c = 0; c < 8; ++c) o[m2][c] = (f32x4)(0.f);
#pragma unroll
      for (int j = 0; j < 4; ++j) { mrow[m2][j] = -1e30f; lrow[m2][j] = 0.f; }
    }
  };
  auto storeO = [&](int qrow0) {
#pragma unroll
    for (int m2 = 0; m2 < 2; ++m2)
#pragma unroll
      for (int c = 0; c < 8; ++c)
#pragma unroll
        for (int j = 0; j < 4; ++j) {
          const float v = o[m2][c][j] * __builtin_amdgcn_rcpf(lrow[m2][j]);
          O[(size_t)(qrow0 + m2 * 16 + 4 * g + j) * Dm + h * Dh + c * 16 + r] = cvt_bf(v);
        }
  };
  auto stageK = [&](int s0, char* dst) {
#pragma unroll
    for (int n = 0; n < 4; ++n) {
      const int L = n * 4096 + tid * 16;
      const int row = L >> 8;
      const int colb = (L & 255) ^ ((row & 7) << 4);
      gl2lds16((const char*)Kb + (size_t)(s0 + row) * (KVSTR * 2) + colb, dst + L);
    }
  };
  auto stageV = [&](int s0) {
#pragma unroll
    for (int n = 0; n < 4; ++n) {
      const int L = n * 4096 + tid * 16;
      const int row = L >> 7;
      const int colb = (L & 127) ^ ((row & 7) << 4);
      gl2lds16((const char*)VT + ((size_t)row * BT + s0) * 2 + colb, Vs + L);
    }
  };

  int qt = qtA;
  int qrow0 = b * Tn + qt * 128 + wq * 32;
  int qmin = qt * 128 + wq * 32;
  loadQ(qrow0);
  resetAcc();
  stageK(b * Tn, smem);
  VMCNT(0);
  BARRIER();

  int cur = 0;
  for (int t = 0; t < ntot; ++t) {
    if (t == nstA) {
      storeO(qrow0);
      qt = qtB;
      qrow0 = b * Tn + qt * 128 + wq * 32;
      qmin = qt * 128 + wq * 32;
      loadQ(qrow0);
      resetAcc();
    }
    const int st = (t < nstA) ? t : t - nstA;
    const int s0 = b * Tn + st * 64;

    stageV(s0);
    {
      const int t1 = t + 1;
      const int st1 = (t1 >= ntot) ? 0 : ((t1 < nstA) ? t1 : t1 - nstA);
      stageK(b * Tn + st1 * 64, smem + ((cur ^ 1) << 14));
    }

    const bool fullmask = (st * 64 >= qmin + 32);
    char* Pw = Ps + wq * 4096;
    if (!fullmask) {
      const char* Kc = smem + (cur << 14);
      f32x4 sf[2][4];
      __builtin_amdgcn_s_setprio(1);
#pragma unroll
      for (int n = 0; n < 4; ++n) {
        f32x4 sa = (f32x4)(0.f), sb = (f32x4)(0.f);
#pragma unroll
        for (int c = 0; c < 4; ++c) {
          const int row = n * 16 + r;
          bf16x8 kf = *(const bf16x8*)(Kc + row * 256 + ((c * 64 + g * 16) ^ ((row & 7) << 4)));
          sa = __builtin_amdgcn_mfma_f32_16x16x32_bf16(qf[0][c], kf, sa, 0, 0, 0);
          sb = __builtin_amdgcn_mfma_f32_16x16x32_bf16(qf[1][c], kf, sb, 0, 0, 0);
        }
        sf[0][n] = sa; sf[1][n] = sb;
      }
      __builtin_amdgcn_s_setprio(0);
      if (st * 64 + 63 > qmin) {
#pragma unroll
        for (int m2 = 0; m2 < 2; ++m2)
#pragma unroll
          for (int n = 0; n < 4; ++n)
#pragma unroll
            for (int j = 0; j < 4; ++j) {
              const int key = st * 64 + n * 16 + r;
              const int q = qmin + m2 * 16 + 4 * g + j;
              if (key > q) sf[m2][n][j] = -1e30f;
            }
      }
      // row max + T13 defer-rescale gate
      float vmax[2][4];
      bool need = false;
#pragma unroll
      for (int m2 = 0; m2 < 2; ++m2)
#pragma unroll
        for (int j = 0; j < 4; ++j) {
          float v = fmaxf(fmaxf(sf[m2][0][j], sf[m2][1][j]), fmaxf(sf[m2][2][j], sf[m2][3][j]));
          v = fmaxf(v, __shfl_xor(v, 1));
          v = fmaxf(v, __shfl_xor(v, 2));
          v = fmaxf(v, __shfl_xor(v, 4));
          v = fmaxf(v, __shfl_xor(v, 8));
          vmax[m2][j] = v;
          need = need || (v > mrow[m2][j] + DEFER);
        }
      if (__any(need)) {
#pragma unroll
        for (int m2 = 0; m2 < 2; ++m2)
#pragma unroll
          for (int j = 0; j < 4; ++j) {
            const float mnew = fmaxf(mrow[m2][j], vmax[m2][j]);
            const float fac = __builtin_amdgcn_exp2f((mrow[m2][j] - mnew) * cl2);
            mrow[m2][j] = mnew;
            lrow[m2][j] *= fac;
#pragma unroll
            for (int c = 0; c < 8; ++c) o[m2][c][j] *= fac;
          }
      }
#pragma unroll
      for (int m2 = 0; m2 < 2; ++m2)
#pragma unroll
        for (int n = 0; n < 4; ++n)
#pragma unroll
          for (int j = 0; j < 4; ++j) {
            const float pv = __builtin_amdgcn_exp2f((sf[m2][n][j] - mrow[m2][j]) * cl2);
            sf[m2][n][j] = pv;
            const int row = m2 * 16 + 4 * g + j;
            *(u16*)(Pw + row * 128 + ((n * 32 + r * 2) ^ ((row & 7) << 4))) = cvt_bf(pv);
          }
#pragma unroll
      for (int m2 = 0; m2 < 2; ++m2)
#pragma unroll
        for (int j = 0; j < 4; ++j) {
          float v = sf[m2][0][j] + sf[m2][1][j] + sf[m2][2][j] + sf[m2][3][j];
          v += __shfl_xor(v, 1);
          v += __shfl_xor(v, 2);
          v += __shfl_xor(v, 4);
          v += __shfl_xor(v, 8);
          lrow[m2][j] += v;
        }
    }

    VMCNT(4);   // own V loads done (K prefetch stays in flight)
    BARRIER();

    if (!fullmask) {
      __builtin_amdgcn_s_setprio(1);
#pragma unroll
      for (int kk = 0; kk < 2; ++kk) {
        if (st * 64 + kk * 32 >= qmin + 32) continue;
        bf16x8 pa0 = *(const bf16x8*)(Pw + r * 128 + ((kk * 64 + g * 16) ^ ((r & 7) << 4)));
        bf16x8 pa1 = *(const bf16x8*)(Pw + (16 + r) * 128 + ((kk * 64 + g * 16) ^ ((r & 7) << 4)));
#pragma unroll
        for (int c = 0; c < 8; ++c) {
          const int row = c * 16 + r;
          bf16x8 vb = *(const bf16x8*)(Vs + row * 128 + ((kk * 64 + g * 16) ^ ((row & 7) << 4)));
          o[0][c] = __builtin_amdgcn_mfma_f32_16x16x32_bf16(pa0, vb, o[0][c], 0, 0, 0);
          o[1][c] = __builtin_amdgcn_mfma_f32_16x16x32_bf16(pa1, vb, o[1][c], 0, 0, 0);
        }
      }
      __builtin_amdgcn_s_setprio(0);
    }

    VMCNT(0);   // K_{t+1} landed
    BARRIER();
    cur ^= 1;
  }
  storeO(qrow0);
}

// ---------------- host launch ----------------
extern "C" void kernel_launch(void* const* d_in, const int* in_sizes, int n_in,
                              void* d_out, int out_size, void* d_ws, size_t ws_size,
                              hipStream_t stream) {
  const float* x  = (const float*)d_in[0];
  // d_in[1] = mask: unused (exactly causal triu(-inf), applied analytically)
  const float* Wq = (const float*)d_in[2];
  const float* bq = (const float*)d_in[3];
  const float* Wk = (const float*)d_in[4];
  const float* bk = (const float*)d_in[5];
  const float* Wv = (const float*)d_in[6];
  const float* bv = (const float*)d_in[7];
  const float* Wo = (const float*)d_in[8];
  const float* bo = (const float*)d_in[9];
  float* out = (float*)d_out;

  char* ws = (char*)d_ws;
  size_t off = 0;
  auto alloc = [&](size_t bytes) {
    char* p = ws + off;
    off += (bytes + 255) & ~(size_t)255;
    return p;
  };
  u16* xb   = (u16*)alloc((size_t)BT * Dm * 2);
  u16* Qb   = (u16*)alloc((size_t)BT * Dm * 2);
  u16* KVb  = (u16*)alloc((size_t)BT * KVSTR * 2);   // [token][K(128)|V(128)]
  u16* VTb  = (u16*)alloc((size_t)BT * Dh * 2);
  u16* Wqt  = (u16*)alloc((size_t)Dm * Dm * 2);
  u16* Wkvt = (u16*)alloc((size_t)Dm * KVSTR * 2);   // [K^T rows | V^T rows]
  u16* Wot  = (u16*)alloc((size_t)Dm * Dm * 2);
  float* bkv = (float*)alloc(KVSTR * sizeof(float));
  u16* Ob   = xb; // x_bf16 dead after projections

  // allow 128KB dynamic LDS for the 256^2 GEMMs (not a stream op; capture-safe)
  hipFuncSetAttribute(reinterpret_cast<const void*>(&k_gemm256<u16>),
                      hipFuncAttributeMaxDynamicSharedMemorySize, 131072);
  hipFuncSetAttribute(reinterpret_cast<const void*>(&k_gemm256<float>),
                      hipFuncAttributeMaxDynamicSharedMemorySize, 131072);

  k_cast_bf16<<<2048, 256, 0, stream>>>(x, xb, BT * Dm / 4);
  dim3 tb(32, 8);
  k_transpose_cast<<<dim3(Dm / 32, Dm / 32), tb, 0, stream>>>(Wq, Wqt, Dm, Dm);
  k_transpose_cast<<<dim3(Dh / 32, Dm / 32), tb, 0, stream>>>(Wk, Wkvt, Dm, Dh);
  k_transpose_cast<<<dim3(Dh / 32, Dm / 32), tb, 0, stream>>>(Wv, Wkvt + (size_t)Dh * Dm, Dm, Dh);
  k_transpose_cast<<<dim3(Dm / 32, Dm / 32), tb, 0, stream>>>(Wo, Wot, Dm, Dm);
  k_concat_bias<<<1, 256, 0, stream>>>(bk, bv, bkv);

  k_gemm256<u16><<<(BT / 256) * (Dm / 256), 512, 131072, stream>>>(xb, Wqt, bq, Qb, BT, Dm, Dm);
  k_gemm_bt<u16><<<dim3(BT / 128, KVSTR / 128), 256, 0, stream>>>(xb, Wkvt, bkv, KVb, BT, KVSTR, Dm);
  k_transpose_bf16<<<dim3(Dh / 32, BT / 32), tb, 0, stream>>>(KVb + Dh, KVSTR, VTb, BT, Dh);

  k_attn<<<512, 256, 0, stream>>>(Qb, KVb, VTb, Ob);

  k_gemm256<float><<<(BT / 256) * (Dm / 256), 512, 131072, stream>>>(Ob, Wot, bo, out, BT, Dm, Dm);
}

// Round 5
// 311.013 us; speedup vs baseline: 1.8800x; 1.1325x over previous
//
#include <hip/hip_runtime.h>
#include <hip/hip_bf16.h>
#include <stdint.h>

#define DEV __device__ __forceinline__

typedef unsigned short u16;
typedef unsigned int u32;
typedef __bf16 bf16x8 __attribute__((ext_vector_type(8)));
typedef float f32x4 __attribute__((ext_vector_type(4)));
typedef u16 u16x4 __attribute__((ext_vector_type(4)));
typedef u32 u32x2 __attribute__((ext_vector_type(2)));
typedef u32 u32x4 __attribute__((ext_vector_type(4)));

typedef __attribute__((address_space(1))) u32 u32_as1;
typedef __attribute__((address_space(3))) u32 u32_as3;

static constexpr int Bn = 4, Tn = 2048, Dm = 2048, Hn = 16, Dh = 128;
static constexpr int BT = Bn * Tn; // 8192
static constexpr int KVSTR = 256;  // fused K|V row stride (elements)

#define VMCNT(n) asm volatile("s_waitcnt vmcnt(" #n ")" ::: "memory")
#define BARRIER() __builtin_amdgcn_s_barrier()

DEV u16 f2bf(float f) {
  u32 u = __builtin_bit_cast(u32, f);
  u += 0x7fffu + ((u >> 16) & 1u);   // RNE
  return (u16)(u >> 16);
}
DEV u16 cvt_bf(float f) { return __builtin_bit_cast(u16, (__bf16)f); }
DEV u32 cvt_pk_bf16(float lo, float hi) {   // u32 = {lo_bf16, hi_bf16<<16}
  u32 r;
  asm("v_cvt_pk_bf16_f32 %0, %1, %2" : "=v"(r) : "v"(lo), "v"(hi));
  return r;
}

// async 16B global->LDS; LDS dest is wave-linear (base + lane*16), so the
// XOR swizzle is applied on the GLOBAL source side (rule #21).
DEV void gl2lds16(const void* g, void* l) {
  __builtin_amdgcn_global_load_lds((u32_as1*)(uintptr_t)g,
                                   (u32_as3*)(u32)(uintptr_t)l, 16, 0, 0);
}

// ---------------- cast f32 -> bf16, vectorized x4 ----------------
__global__ __launch_bounds__(256) void k_cast_bf16(const float* __restrict__ in,
                                                   u16* __restrict__ out, int n4) {
  int i = blockIdx.x * 256 + threadIdx.x;
  int stride = gridDim.x * 256;
  for (; i < n4; i += stride) {
    f32x4 v = ((const f32x4*)in)[i];
    u16x4 o;
    o.x = f2bf(v.x); o.y = f2bf(v.y); o.z = f2bf(v.z); o.w = f2bf(v.w);
    ((u16x4*)out)[i] = o;
  }
}

// ---------------- transpose-cast f32[R][C] -> bf16[C][R] ----------------
__global__ __launch_bounds__(256) void k_transpose_cast(const float* __restrict__ in,
                                                        u16* __restrict__ out,
                                                        int R, int C) {
  __shared__ float t[32][33];
  const int r0 = blockIdx.y * 32, c0 = blockIdx.x * 32;
  const int x = threadIdx.x, y = threadIdx.y; // (32,8)
#pragma unroll
  for (int i = 0; i < 4; ++i)
    t[y + i * 8][x] = in[(size_t)(r0 + y + i * 8) * C + c0 + x];
  __syncthreads();
#pragma unroll
  for (int i = 0; i < 4; ++i)
    out[(size_t)(c0 + y + i * 8) * R + r0 + x] = f2bf(t[x][y + i * 8]);
}

// ---------------- transpose bf16 in[R][inStride] (window C) -> out[C][R] ----
__global__ __launch_bounds__(256) void k_transpose_bf16(const u16* __restrict__ in,
                                                        int inStride,
                                                        u16* __restrict__ out,
                                                        int R, int C) {
  __shared__ u16 t[32][34];
  const int r0 = blockIdx.y * 32, c0 = blockIdx.x * 32;
  const int x = threadIdx.x, y = threadIdx.y;
#pragma unroll
  for (int i = 0; i < 4; ++i)
    t[y + i * 8][x] = in[(size_t)(r0 + y + i * 8) * inStride + c0 + x];
  __syncthreads();
#pragma unroll
  for (int i = 0; i < 4; ++i)
    out[(size_t)(c0 + y + i * 8) * R + r0 + x] = t[x][y + i * 8];
}

__global__ void k_concat_bias(const float* __restrict__ a, const float* __restrict__ b,
                              float* __restrict__ dst) {
  int i = threadIdx.x; // 256
  dst[i] = (i < 128) ? a[i] : b[i - 128];
}

// ---------------- GEMM 128x128 (m97 structure) — used for the small KV proj ----
template <typename OutT>
__global__ __launch_bounds__(256) void k_gemm_bt(const u16* __restrict__ A,
                                                 const u16* __restrict__ Bt,
                                                 const float* __restrict__ bias,
                                                 OutT* __restrict__ C,
                                                 int M, int N, int K) {
  __shared__ __align__(128) char smem[32768];
  char* As = smem;
  char* Bs = smem + 16384;
  const int tid = threadIdx.x;
  const int wid = tid >> 6, lane = tid & 63;
  const int g = lane >> 4, r = lane & 15;
  const int wr = wid >> 1, wc = wid & 1;
  const int m0 = blockIdx.x * 128, n0 = blockIdx.y * 128;

  f32x4 acc[4][4];
#pragma unroll
  for (int m = 0; m < 4; ++m)
#pragma unroll
    for (int n = 0; n < 4; ++n) acc[m][n] = (f32x4)(0.f);

  for (int k0 = 0; k0 < K; k0 += 64) {
#pragma unroll
    for (int n = 0; n < 4; ++n) {
      const int L = n * 4096 + tid * 16;
      const int row = L >> 7;
      const int colb = (L & 127) ^ ((row & 7) << 4);
      gl2lds16((const char*)A + ((size_t)(m0 + row) * K + k0) * 2 + colb, As + L);
      gl2lds16((const char*)Bt + ((size_t)(n0 + row) * K + k0) * 2 + colb, Bs + L);
    }
    __syncthreads();
#pragma unroll
    for (int kk = 0; kk < 2; ++kk) {
      bf16x8 a[4], b[4];
#pragma unroll
      for (int m = 0; m < 4; ++m) {
        const int row = wr * 64 + m * 16 + r;
        a[m] = *(const bf16x8*)(As + row * 128 + ((kk * 64 + g * 16) ^ ((row & 7) << 4)));
      }
#pragma unroll
      for (int n = 0; n < 4; ++n) {
        const int row = wc * 64 + n * 16 + r;
        b[n] = *(const bf16x8*)(Bs + row * 128 + ((kk * 64 + g * 16) ^ ((row & 7) << 4)));
      }
#pragma unroll
      for (int m = 0; m < 4; ++m)
#pragma unroll
        for (int n = 0; n < 4; ++n)
          acc[m][n] = __builtin_amdgcn_mfma_f32_16x16x32_bf16(a[m], b[n], acc[m][n], 0, 0, 0);
    }
    __syncthreads();
  }

#pragma unroll
  for (int n = 0; n < 4; ++n) {
    const int col = n0 + wc * 64 + n * 16 + r;
    const float bv = bias[col];
#pragma unroll
    for (int m = 0; m < 4; ++m) {
#pragma unroll
      for (int j = 0; j < 4; ++j) {
        const int grow = m0 + wr * 64 + m * 16 + 4 * g + j;
        const float v = acc[m][n][j] + bv;
        if constexpr (sizeof(OutT) == 2)
          ((u16*)C)[(size_t)grow * N + col] = f2bf(v);
        else
          ((float*)C)[(size_t)grow * N + col] = v;
      }
    }
  }
}

// ---------------- GEMM 256x256, 8-wave, 4-phase/K-tile, counted vmcnt ----------
template <typename OutT>
__global__ __launch_bounds__(512, 2) void k_gemm256(const u16* __restrict__ A,
                                                    const u16* __restrict__ Bt,
                                                    const float* __restrict__ bias,
                                                    OutT* __restrict__ C,
                                                    int M, int N, int K) {
  extern __shared__ char smem[];
  const int tid = threadIdx.x;
  const int wid = tid >> 6, lane = tid & 63;
  const int g = lane >> 4, r = lane & 15;
  const int wm = wid >> 2, wn = wid & 3;

  const int nbn = N >> 8;
  const int cpx = gridDim.x >> 3;
  const int linear = (blockIdx.x & 7) * cpx + (blockIdx.x >> 3);
  const int m0 = (linear / nbn) << 8;
  const int n0 = (linear % nbn) << 8;

  const int rowInCh = lane >> 3;
  const int colb = ((lane & 7) << 4) ^ (rowInCh << 4);
  const char* srcA0; const char* srcA1; const char* srcA2; const char* srcA3;
  const char* srcB0; const char* srcB1; const char* srcB2; const char* srcB3;
  int ldsA[4], ldsB[4];
  {
    const int wnh = (wid >> 1) & 1;
    const int cbb = ((wid >> 2) << 1) | (wid & 1);
    const char* sa[4]; const char* sb[4];
#pragma unroll
    for (int i = 0; i < 4; ++i) {
      const int chA = ((wid & 3) << 2) + i;
      const int lrA = (wm << 7) + (chA << 3) + rowInCh;
      sa[i] = (const char*)A + ((size_t)(m0 + lrA) * K) * 2 + colb;
      ldsA[i] = ((wm << 7) + (chA << 3)) * 128 + lane * 16;
      const int chB = (cbb << 2) + i;
      const int lrB = (wnh << 7) + (chB << 3) + rowInCh;
      sb[i] = (const char*)Bt + ((size_t)(n0 + lrB) * K) * 2 + colb;
      ldsB[i] = 32768 + ((wnh << 7) + (chB << 3)) * 128 + lane * 16;
    }
    srcA0 = sa[0]; srcA1 = sa[1]; srcA2 = sa[2]; srcA3 = sa[3];
    srcB0 = sb[0]; srcB1 = sb[1]; srcB2 = sb[2]; srcB3 = sb[3];
  }

  auto stage = [&](int t, int b) {
    const size_t ko = (size_t)t * 128;
    char* base = smem + (b << 16);
    gl2lds16(srcA0 + ko, base + ldsA[0]);
    gl2lds16(srcA1 + ko, base + ldsA[1]);
    gl2lds16(srcA2 + ko, base + ldsA[2]);
    gl2lds16(srcA3 + ko, base + ldsA[3]);
    gl2lds16(srcB0 + ko, base + ldsB[0]);
    gl2lds16(srcB1 + ko, base + ldsB[1]);
    gl2lds16(srcB2 + ko, base + ldsB[2]);
    gl2lds16(srcB3 + ko, base + ldsB[3]);
  };

  f32x4 acc[8][4];
#pragma unroll
  for (int m = 0; m < 8; ++m)
#pragma unroll
    for (int n = 0; n < 4; ++n) acc[m][n] = (f32x4)(0.f);

  auto readA = [&](const char* Ab, int qm, bf16x8 (&a)[8]) {
#pragma unroll
    for (int m = 0; m < 4; ++m) {
      const int row = (wm << 7) + ((qm * 4 + m) << 4) + r;
#pragma unroll
      for (int kk = 0; kk < 2; ++kk)
        a[m * 2 + kk] = *(const bf16x8*)(Ab + row * 128 + ((kk * 64 + g * 16) ^ ((row & 7) << 4)));
    }
  };
  auto readB = [&](const char* Bb, int qn, bf16x8 (&b)[4]) {
#pragma unroll
    for (int n = 0; n < 2; ++n) {
      const int row = (wn << 6) + ((qn * 2 + n) << 4) + r;
#pragma unroll
      for (int kk = 0; kk < 2; ++kk)
        b[n * 2 + kk] = *(const bf16x8*)(Bb + row * 128 + ((kk * 64 + g * 16) ^ ((row & 7) << 4)));
    }
  };
  auto mfmaQ = [&](const bf16x8 (&a)[8], const bf16x8 (&b)[4], int qm, int qn) {
    __builtin_amdgcn_s_setprio(1);
#pragma unroll
    for (int m = 0; m < 4; ++m)
#pragma unroll
      for (int n = 0; n < 2; ++n)
#pragma unroll
        for (int kk = 0; kk < 2; ++kk)
          acc[qm * 4 + m][qn * 2 + n] = __builtin_amdgcn_mfma_f32_16x16x32_bf16(
              a[m * 2 + kk], b[n * 2 + kk], acc[qm * 4 + m][qn * 2 + n], 0, 0, 0);
    __builtin_amdgcn_s_setprio(0);
  };

  const int NT = K >> 6;
  stage(0, 0);
  stage(1, 1);
  VMCNT(8);
  BARRIER();

  bf16x8 a0[8], a1[8], b0[4], b1[4];
  for (int t = 0; t < NT; ++t) {
    const char* Ab = smem + ((t & 1) << 16);
    const char* Bb = Ab + 32768;
    readA(Ab, 0, a0);
    readB(Bb, 0, b0);
    BARRIER();
    mfmaQ(a0, b0, 0, 0);
    BARRIER();
    readB(Bb, 1, b1);
    BARRIER();
    mfmaQ(a0, b1, 0, 1);
    BARRIER();
    readA(Ab, 1, a1);
    BARRIER();
    mfmaQ(a1, b1, 1, 1);
    BARRIER();
    if (t + 2 < NT) {
      stage(t + 2, t & 1);
      mfmaQ(a1, b0, 1, 0);
      VMCNT(8);
    } else {
      mfmaQ(a1, b0, 1, 0);
      VMCNT(0);
    }
    BARRIER();
  }

#pragma unroll
  for (int n = 0; n < 4; ++n) {
    const int col = n0 + wn * 64 + n * 16 + r;
    const float bv = bias[col];
#pragma unroll
    for (int m = 0; m < 8; ++m) {
#pragma unroll
      for (int j = 0; j < 4; ++j) {
        const int grow = m0 + wm * 128 + m * 16 + 4 * g + j;
        const float v = acc[m][n][j] + bv;
        if constexpr (sizeof(OutT) == 2)
          ((u16*)C)[(size_t)grow * N + col] = cvt_bf(v);
        else
          ((float*)C)[(size_t)grow * N + col] = v;
      }
    }
  }
}

// ---------------- flash attention (MQA), causal, SWAPPED QK^T ----------------
// mfma(K,Q): lane owns score rows for q = lane&15 (+16 per q-frag) -> in-lane
// softmax (2 shfl per reduce), P packed in-lane via cvt_pk with kv-permutation
// pi that is cancelled by reading V B-frags as 2x ds_read_b64 at pi's offsets.
// No P LDS, no P shuffles. Staging/pipeline identical to R3.
__global__ __launch_bounds__(256, 2) void k_attn(const u16* __restrict__ Q,
                                                 const u16* __restrict__ Kb,
                                                 const u16* __restrict__ VT,
                                                 u16* __restrict__ O) {
  __shared__ __align__(1024) char smem[49152];
  // K dbuf at smem + (cur<<14) (2 x 16KB, [64 kv][256B] swizzled)
  char* Vs = smem + 32768;                   // V^T: [128 d][128B kv], swizzled

  const int tid = threadIdx.x;
  const int wq = tid >> 6, lane = tid & 63;
  const int g = lane >> 4, r = lane & 15;

  const int bid = blockIdx.x;
  const int xcd = bid & 7, ii = bid >> 3;
  const int b = xcd >> 1;
  const int h = ((xcd & 1) << 3) | (ii >> 3);
  const int p = ii & 7;
  const int qtA = p, qtB = 15 - p;
  const int nstA = 2 * qtA + 2;
  const int ntot = nstA + 2 * qtB + 2;       // = 34

  const float cl2 = 0.1275174147f;           // log2(e)/sqrt(128)
  const float DEFER = 62.736f;               // -> max exp2 arg = 8 (pv <= 256)

  bf16x8 qf[2][4];
  f32x4 o[2][8];
  float mrow[2], lrow[2];

  auto loadQ = [&](int qrow0) {
#pragma unroll
    for (int m2 = 0; m2 < 2; ++m2)
#pragma unroll
      for (int c = 0; c < 4; ++c)
        qf[m2][c] = *(const bf16x8*)(Q + (size_t)(qrow0 + m2 * 16 + r) * Dm + h * Dh + c * 32 + g * 8);
  };
  auto resetAcc = [&]() {
#pragma unroll
    for (int m2 = 0; m2 < 2; ++m2) {
#pragma unroll
      for (int c = 0; c < 8; ++c) o[m2][c] = (f32x4)(0.f);
      mrow[m2] = -1e30f; lrow[m2] = 0.f;
    }
  };
  auto storeO = [&](int qrow0) {
#pragma unroll
    for (int m2 = 0; m2 < 2; ++m2) {
      float linv[4];
#pragma unroll
      for (int j = 0; j < 4; ++j)
        linv[j] = __builtin_amdgcn_rcpf(__shfl(lrow[m2], 20 * g + j));
#pragma unroll
      for (int c = 0; c < 8; ++c)
#pragma unroll
        for (int j = 0; j < 4; ++j)
          O[(size_t)(qrow0 + m2 * 16 + 4 * g + j) * Dm + h * Dh + c * 16 + r] =
              cvt_bf(o[m2][c][j] * linv[j]);
    }
  };
  auto stageK = [&](int s0, char* dst) {
#pragma unroll
    for (int n = 0; n < 4; ++n) {
      const int L = n * 4096 + tid * 16;
      const int row = L >> 8;
      const int colb = (L & 255) ^ ((row & 7) << 4);
      gl2lds16((const char*)Kb + (size_t)(s0 + row) * (KVSTR * 2) + colb, dst + L);
    }
  };
  auto stageV = [&](int s0) {
#pragma unroll
    for (int n = 0; n < 4; ++n) {
      const int L = n * 4096 + tid * 16;
      const int row = L >> 7;
      const int colb = (L & 127) ^ ((row & 7) << 4);
      gl2lds16((const char*)VT + ((size_t)row * BT + s0) * 2 + colb, Vs + L);
    }
  };

  int qt = qtA;
  int qrow0 = b * Tn + qt * 128 + wq * 32;
  int qmin = qt * 128 + wq * 32;
  loadQ(qrow0);
  resetAcc();
  stageK(b * Tn, smem);
  VMCNT(0);
  BARRIER();

  int cur = 0;
  for (int t = 0; t < ntot; ++t) {
    if (t == nstA) {
      storeO(qrow0);
      qt = qtB;
      qrow0 = b * Tn + qt * 128 + wq * 32;
      qmin = qt * 128 + wq * 32;
      loadQ(qrow0);
      resetAcc();
    }
    const int st = (t < nstA) ? t : t - nstA;
    const int s0 = b * Tn + st * 64;

    stageV(s0);
    {
      const int t1 = t + 1;
      const int st1 = (t1 >= ntot) ? 0 : ((t1 < nstA) ? t1 : t1 - nstA);
      stageK(b * Tn + st1 * 64, smem + ((cur ^ 1) << 14));
    }

    const bool fullmask = (st * 64 >= qmin + 32);
    u32x4 pau[2][2];   // [qfrag][kk] packed P A-frags (in-lane)
    if (!fullmask) {
      const char* Kc = smem + (cur << 14);
      f32x4 sf[2][4];
      __builtin_amdgcn_s_setprio(1);
#pragma unroll
      for (int n = 0; n < 4; ++n) {
        f32x4 sa = (f32x4)(0.f), sb = (f32x4)(0.f);
#pragma unroll
        for (int c = 0; c < 4; ++c) {
          const int row = n * 16 + r;
          bf16x8 kf = *(const bf16x8*)(Kc + row * 256 + ((c * 64 + g * 16) ^ ((row & 7) << 4)));
          sa = __builtin_amdgcn_mfma_f32_16x16x32_bf16(kf, qf[0][c], sa, 0, 0, 0);
          sb = __builtin_amdgcn_mfma_f32_16x16x32_bf16(kf, qf[1][c], sb, 0, 0, 0);
        }
        sf[0][n] = sa; sf[1][n] = sb;
      }
      __builtin_amdgcn_s_setprio(0);
      // causal mask: key = st*64 + n*16 + 4g + j ; q = qmin + m2*16 + r
      if (st * 64 + 63 > qmin) {
#pragma unroll
        for (int m2 = 0; m2 < 2; ++m2) {
          const int q = qmin + m2 * 16 + r;
#pragma unroll
          for (int n = 0; n < 4; ++n)
#pragma unroll
            for (int j = 0; j < 4; ++j) {
              const int key = st * 64 + n * 16 + 4 * g + j;
              if (key > q) sf[m2][n][j] = -1e30f;
            }
        }
      }
      // in-lane row max (16 vals) + 2 shfl; T13 defer gate
      float vmax[2];
      bool need = false;
#pragma unroll
      for (int m2 = 0; m2 < 2; ++m2) {
        f32x4 t4;
#pragma unroll
        for (int j = 0; j < 4; ++j)
          t4[j] = fmaxf(fmaxf(sf[m2][0][j], sf[m2][1][j]), fmaxf(sf[m2][2][j], sf[m2][3][j]));
        float v = fmaxf(fmaxf(t4[0], t4[1]), fmaxf(t4[2], t4[3]));
        v = fmaxf(v, __shfl_xor(v, 16));
        v = fmaxf(v, __shfl_xor(v, 32));
        vmax[m2] = v;
        need = need || (v > mrow[m2] + DEFER);
      }
      if (__any(need)) {
#pragma unroll
        for (int m2 = 0; m2 < 2; ++m2) {
          const float mnew = fmaxf(mrow[m2], vmax[m2]);
          const float fac = __builtin_amdgcn_exp2f((mrow[m2] - mnew) * cl2);
          mrow[m2] = mnew;
          lrow[m2] *= fac;
#pragma unroll
          for (int j = 0; j < 4; ++j) {
            const float fb = __shfl(fac, 20 * g + j);   // lane g*16 + 4g + j
#pragma unroll
            for (int c = 0; c < 8; ++c) o[m2][c][j] *= fb;
          }
        }
      }
      // exp + in-lane pack to PV A-frags: slot(k=8g+jj) <- S[q][pi(kk,g,jj)]
      float rs[2] = {0.f, 0.f};
#pragma unroll
      for (int m2 = 0; m2 < 2; ++m2) {
#pragma unroll
        for (int n = 0; n < 4; ++n) {
          const float p0 = __builtin_amdgcn_exp2f((sf[m2][n][0] - mrow[m2]) * cl2);
          const float p1 = __builtin_amdgcn_exp2f((sf[m2][n][1] - mrow[m2]) * cl2);
          const float p2 = __builtin_amdgcn_exp2f((sf[m2][n][2] - mrow[m2]) * cl2);
          const float p3 = __builtin_amdgcn_exp2f((sf[m2][n][3] - mrow[m2]) * cl2);
          rs[m2] += (p0 + p1) + (p2 + p3);
          pau[m2][n >> 1][(n & 1) * 2]     = cvt_pk_bf16(p0, p1);
          pau[m2][n >> 1][(n & 1) * 2 + 1] = cvt_pk_bf16(p2, p3);
        }
        float v = rs[m2];
        v += __shfl_xor(v, 16);
        v += __shfl_xor(v, 32);
        lrow[m2] += v;
      }
    }

    VMCNT(4);   // own V loads done (K prefetch stays in flight)
    BARRIER();

    if (!fullmask) {
      __builtin_amdgcn_s_setprio(1);
#pragma unroll
      for (int kk = 0; kk < 2; ++kk) {
        if (st * 64 + kk * 32 >= qmin + 32) continue;
        const bf16x8 pa0 = __builtin_bit_cast(bf16x8, pau[0][kk]);
        const bf16x8 pa1 = __builtin_bit_cast(bf16x8, pau[1][kk]);
#pragma unroll
        for (int c = 0; c < 8; ++c) {
          const int row = c * 16 + r;
          const int swz = (row & 7) << 4;
          const u32x2 lo = *(const u32x2*)(Vs + row * 128 + ((kk * 64 + 8 * g) ^ swz));
          const u32x2 hi = *(const u32x2*)(Vs + row * 128 + ((kk * 64 + 32 + 8 * g) ^ swz));
          u32x4 vbu;
          vbu.x = lo.x; vbu.y = lo.y; vbu.z = hi.x; vbu.w = hi.y;
          const bf16x8 vb = __builtin_bit_cast(bf16x8, vbu);
          o[0][c] = __builtin_amdgcn_mfma_f32_16x16x32_bf16(pa0, vb, o[0][c], 0, 0, 0);
          o[1][c] = __builtin_amdgcn_mfma_f32_16x16x32_bf16(pa1, vb, o[1][c], 0, 0, 0);
        }
      }
      __builtin_amdgcn_s_setprio(0);
    }

    VMCNT(0);   // K_{t+1} landed
    BARRIER();
    cur ^= 1;
  }
  storeO(qrow0);
}

// ---------------- host launch ----------------
extern "C" void kernel_launch(void* const* d_in, const int* in_sizes, int n_in,
                              void* d_out, int out_size, void* d_ws, size_t ws_size,
                              hipStream_t stream) {
  const float* x  = (const float*)d_in[0];
  // d_in[1] = mask: unused (exactly causal triu(-inf), applied analytically)
  const float* Wq = (const float*)d_in[2];
  const float* bq = (const float*)d_in[3];
  const float* Wk = (const float*)d_in[4];
  const float* bk = (const float*)d_in[5];
  const float* Wv = (const float*)d_in[6];
  const float* bv = (const float*)d_in[7];
  const float* Wo = (const float*)d_in[8];
  const float* bo = (const float*)d_in[9];
  float* out = (float*)d_out;

  char* ws = (char*)d_ws;
  size_t off = 0;
  auto alloc = [&](size_t bytes) {
    char* p = ws + off;
    off += (bytes + 255) & ~(size_t)255;
    return p;
  };
  u16* xb   = (u16*)alloc((size_t)BT * Dm * 2);
  u16* Qb   = (u16*)alloc((size_t)BT * Dm * 2);
  u16* KVb  = (u16*)alloc((size_t)BT * KVSTR * 2);   // [token][K(128)|V(128)]
  u16* VTb  = (u16*)alloc((size_t)BT * Dh * 2);
  u16* Wqt  = (u16*)alloc((size_t)Dm * Dm * 2);
  u16* Wkvt = (u16*)alloc((size_t)Dm * KVSTR * 2);   // [K^T rows | V^T rows]
  u16* Wot  = (u16*)alloc((size_t)Dm * Dm * 2);
  float* bkv = (float*)alloc(KVSTR * sizeof(float));
  u16* Ob   = xb; // x_bf16 dead after projections

  hipFuncSetAttribute(reinterpret_cast<const void*>(&k_gemm256<u16>),
                      hipFuncAttributeMaxDynamicSharedMemorySize, 131072);
  hipFuncSetAttribute(reinterpret_cast<const void*>(&k_gemm256<float>),
                      hipFuncAttributeMaxDynamicSharedMemorySize, 131072);

  k_cast_bf16<<<2048, 256, 0, stream>>>(x, xb, BT * Dm / 4);
  dim3 tb(32, 8);
  k_transpose_cast<<<dim3(Dm / 32, Dm / 32), tb, 0, stream>>>(Wq, Wqt, Dm, Dm);
  k_transpose_cast<<<dim3(Dh / 32, Dm / 32), tb, 0, stream>>>(Wk, Wkvt, Dm, Dh);
  k_transpose_cast<<<dim3(Dh / 32, Dm / 32), tb, 0, stream>>>(Wv, Wkvt + (size_t)Dh * Dm, Dm, Dh);
  k_transpose_cast<<<dim3(Dm / 32, Dm / 32), tb, 0, stream>>>(Wo, Wot, Dm, Dm);
  k_concat_bias<<<1, 256, 0, stream>>>(bk, bv, bkv);

  k_gemm256<u16><<<(BT / 256) * (Dm / 256), 512, 131072, stream>>>(xb, Wqt, bq, Qb, BT, Dm, Dm);
  k_gemm_bt<u16><<<dim3(BT / 128, KVSTR / 128), 256, 0, stream>>>(xb, Wkvt, bkv, KVb, BT, KVSTR, Dm);
  k_transpose_bf16<<<dim3(Dh / 32, BT / 32), tb, 0, stream>>>(KVb + Dh, KVSTR, VTb, BT, Dh);

  k_attn<<<512, 256, 0, stream>>>(Qb, KVb, VTb, Ob);

  k_gemm256<float><<<(BT / 256) * (Dm / 256), 512, 131072, stream>>>(Ob, Wot, bo, out, BT, Dm, Dm);
}